// Round 12
// baseline (359.537 us; speedup 1.0000x reference)
//
#include <hip/hip_runtime.h>

#define TT 512
#define LOG2E 1.44269504088896340736f

// ---- DPP helpers (rows of 16 lanes) ----
template <int N>
__device__ __forceinline__ int rorki_(int v) {           // row_ror:N, depth-1 fan-out
    return __builtin_amdgcn_update_dpp(v, v, 0x120 + N, 0xf, 0xf, true);
}
template <int N>
__device__ __forceinline__ float rorkf_(float v) { return __int_as_float(rorki_<N>(__float_as_int(v))); }
template <int C>
__device__ __forceinline__ float shrf_(float v) {        // row_shr:N, shifted-in -> 0
    return __int_as_float(__builtin_amdgcn_update_dpp(0, __float_as_int(v), C, 0xf, 0xf, true));
}
__device__ __forceinline__ float sgm_(float v) {         // sigmoid, arg pre-scaled by log2e
    return __builtin_amdgcn_rcpf(1.f + __builtin_amdgcn_exp2f(-v));
}

__launch_bounds__(64)
__attribute__((amdgpu_waves_per_eu(1)))   // budget only; VGPR ~132 -> 2 waves/SIMD resident
__global__ void gru_fan2(const float* __restrict__ x,
                         const float* __restrict__ W1, const float* __restrict__ Ur1,
                         const float* __restrict__ b1,
                         const float* __restrict__ W2, const float* __restrict__ Ur2,
                         const float* __restrict__ b2,
                         const float* __restrict__ Wd, const float* __restrict__ bd,
                         const float* __restrict__ Wo, const float* __restrict__ bo,
                         float* __restrict__ out)
{
    const int lane = threadIdx.x & 63;
    const int g    = lane >> 5;         // 2 rows/wave; 16-lane groups 1,3 mirror 0,2
    const int j    = lane & 15;         // GRU2 / dense unit
    const int u1   = j & 7;             // GRU1 unit (pair-duplicated)
    const int hi   = j >> 3;            // 0: z-side, 1: r-side of the GRU1 pair
    const int gcol = u1 + 8 * hi;       // z column (0..7) or r column (8..15)
    const int row  = blockIdx.x * 2 + g;
    const bool ishi = (hi != 0);
    const bool isw  = (j == 15) && (((lane >> 4) & 1) == 0);  // one store per row

    const float* xbase = x + (size_t)blockIdx.x * 2 * TT * 8;
    const int    xoff  = g * TT * 8 + u1;
    float* outrow = out + (size_t)row * TT;

    // ---- trace the DIRECT ror:k permutation (layout-proof weight order) ----
    int Lk[16];
    Lk[0]  = j;
    Lk[1]  = rorki_<1>(j);   Lk[2]  = rorki_<2>(j);   Lk[3]  = rorki_<3>(j);
    Lk[4]  = rorki_<4>(j);   Lk[5]  = rorki_<5>(j);   Lk[6]  = rorki_<6>(j);
    Lk[7]  = rorki_<7>(j);   Lk[8]  = rorki_<8>(j);   Lk[9]  = rorki_<9>(j);
    Lk[10] = rorki_<10>(j);  Lk[11] = rorki_<11>(j);  Lk[12] = rorki_<12>(j);
    Lk[13] = rorki_<13>(j);  Lk[14] = rorki_<14>(j);  Lk[15] = rorki_<15>(j);

    // ---- weights (ror:k-ordered; z/r pre-scaled by log2e) ----
    float q2z[16], q2r[16], q2h[16], wdk[16];      // h2 fan (16 taps)
#pragma unroll
    for (int k = 0; k < 16; ++k) {
        const int s2 = Lk[k];
        q2z[k] = LOG2E * Ur2[s2 * 48 + j];
        q2r[k] = LOG2E * Ur2[s2 * 48 + 16 + j];
        q2h[k] = Ur2[s2 * 48 + 32 + j];
        wdk[k] = Wd[s2 * 16 + j];
    }
    float p2z[8], p2r[8], p2h[8], Ch[8], Qh[8];    // h1 fan (8 taps)
    float Ax[8], Wx[8];                            // x fan (8 taps)
#pragma unroll
    for (int k = 0; k < 8; ++k) {
        const int s1 = Lk[k] & 7;
        p2z[k] = LOG2E * W2[s1 * 48 + j];
        p2r[k] = LOG2E * W2[s1 * 48 + 16 + j];
        p2h[k] = W2[s1 * 48 + 32 + j];
        Ch[k]  = LOG2E * Ur1[s1 * 24 + gcol];
        Qh[k]  = Ur1[s1 * 24 + 16 + u1];
        Ax[k]  = LOG2E * W1[s1 * 24 + gcol];
        Wx[k]  = W1[s1 * 24 + 16 + u1];
    }
    const float bAzr = LOG2E * (b1[gcol] + b1[24 + gcol]);
    const float bGh  = b1[16 + u1];
    const float bIh  = b1[40 + u1];
    const float bA2  = LOG2E * (b2[j] + b2[48 + j]);
    const float bB2  = LOG2E * (b2[16 + j] + b2[64 + j]);
    const float bC2  = b2[80 + j];
    const float bD2  = b2[32 + j];
    const float bdj  = bd[j], woj = Wo[j], boo = bo[0];

    float h1own = 0.f, h2own = 0.f;
    float azrP = bAzr, ihP = bIh;                  // carried GRU1 h-side partials

    float xA = xbase[0 * 8 + xoff];
    float xB = xbase[1 * 8 + xoff];
    float xC = xbase[2 * 8 + xoff];

#define GSTEP(SS, XCUR, XFILL)                                                   \
    {                                                                            \
        const int s = (SS);                                                      \
        /* h2 fan-out: 15 independent depth-1 DPPs from h2own */                 \
        const float h0 = h2own;                                                  \
        const float t1 = rorkf_<1>(h0),  t2  = rorkf_<2>(h0);                    \
        const float t3 = rorkf_<3>(h0),  t4  = rorkf_<4>(h0);                    \
        const float t5 = rorkf_<5>(h0),  t6  = rorkf_<6>(h0);                    \
        const float t7 = rorkf_<7>(h0),  t8  = rorkf_<8>(h0);                    \
        const float t9 = rorkf_<9>(h0),  t10 = rorkf_<10>(h0);                   \
        const float t11 = rorkf_<11>(h0), t12 = rorkf_<12>(h0);                  \
        const float t13 = rorkf_<13>(h0), t14 = rorkf_<14>(h0);                  \
        const float t15 = rorkf_<15>(h0);                                        \
        float za0 = bA2, ra0 = bB2, ha0 = bC2, da0 = bdj;                        \
        float za1 = 0.f, ra1 = 0.f, ha1 = 0.f, da1 = 0.f;                        \
        za0 = fmaf(h0,  q2z[0], za0);  ra0 = fmaf(h0,  q2r[0], ra0);             \
        ha0 = fmaf(h0,  q2h[0], ha0);  da0 = fmaf(h0,  wdk[0], da0);             \
        za0 = fmaf(t1,  q2z[1], za0);  ra0 = fmaf(t1,  q2r[1], ra0);             \
        ha0 = fmaf(t1,  q2h[1], ha0);  da0 = fmaf(t1,  wdk[1], da0);             \
        za0 = fmaf(t2,  q2z[2], za0);  ra0 = fmaf(t2,  q2r[2], ra0);             \
        ha0 = fmaf(t2,  q2h[2], ha0);  da0 = fmaf(t2,  wdk[2], da0);             \
        za0 = fmaf(t3,  q2z[3], za0);  ra0 = fmaf(t3,  q2r[3], ra0);             \
        ha0 = fmaf(t3,  q2h[3], ha0);  da0 = fmaf(t3,  wdk[3], da0);             \
        za0 = fmaf(t4,  q2z[4], za0);  ra0 = fmaf(t4,  q2r[4], ra0);             \
        ha0 = fmaf(t4,  q2h[4], ha0);  da0 = fmaf(t4,  wdk[4], da0);             \
        za0 = fmaf(t5,  q2z[5], za0);  ra0 = fmaf(t5,  q2r[5], ra0);             \
        ha0 = fmaf(t5,  q2h[5], ha0);  da0 = fmaf(t5,  wdk[5], da0);             \
        za0 = fmaf(t6,  q2z[6], za0);  ra0 = fmaf(t6,  q2r[6], ra0);             \
        ha0 = fmaf(t6,  q2h[6], ha0);  da0 = fmaf(t6,  wdk[6], da0);             \
        za0 = fmaf(t7,  q2z[7], za0);  ra0 = fmaf(t7,  q2r[7], ra0);             \
        ha0 = fmaf(t7,  q2h[7], ha0);  da0 = fmaf(t7,  wdk[7], da0);             \
        za1 = fmaf(t8,  q2z[8], za1);  ra1 = fmaf(t8,  q2r[8], ra1);             \
        ha1 = fmaf(t8,  q2h[8], ha1);  da1 = fmaf(t8,  wdk[8], da1);             \
        za1 = fmaf(t9,  q2z[9], za1);  ra1 = fmaf(t9,  q2r[9], ra1);             \
        ha1 = fmaf(t9,  q2h[9], ha1);  da1 = fmaf(t9,  wdk[9], da1);             \
        za1 = fmaf(t10, q2z[10], za1); ra1 = fmaf(t10, q2r[10], ra1);            \
        ha1 = fmaf(t10, q2h[10], ha1); da1 = fmaf(t10, wdk[10], da1);            \
        za1 = fmaf(t11, q2z[11], za1); ra1 = fmaf(t11, q2r[11], ra1);            \
        ha1 = fmaf(t11, q2h[11], ha1); da1 = fmaf(t11, wdk[11], da1);            \
        za1 = fmaf(t12, q2z[12], za1); ra1 = fmaf(t12, q2r[12], ra1);            \
        ha1 = fmaf(t12, q2h[12], ha1); da1 = fmaf(t12, wdk[12], da1);            \
        za1 = fmaf(t13, q2z[13], za1); ra1 = fmaf(t13, q2r[13], ra1);            \
        ha1 = fmaf(t13, q2h[13], ha1); da1 = fmaf(t13, wdk[13], da1);            \
        za1 = fmaf(t14, q2z[14], za1); ra1 = fmaf(t14, q2r[14], ra1);            \
        ha1 = fmaf(t14, q2h[14], ha1); da1 = fmaf(t14, wdk[14], da1);            \
        za1 = fmaf(t15, q2z[15], za1); ra1 = fmaf(t15, q2r[15], ra1);            \
        ha1 = fmaf(t15, q2h[15], ha1); da1 = fmaf(t15, wdk[15], da1);            \
        /* x fan-out: 7 depth-1 DPPs from XCUR */                                \
        const float x0 = XCUR;                                                   \
        const float u1v = rorkf_<1>(x0), u2v = rorkf_<2>(x0);                    \
        const float u3v = rorkf_<3>(x0), u4v = rorkf_<4>(x0);                    \
        const float u5v = rorkf_<5>(x0), u6v = rorkf_<6>(x0);                    \
        const float u7v = rorkf_<7>(x0);                                         \
        float ax0 = azrP, ax1 = 0.f, gh0 = bGh, gh1 = 0.f;                       \
        ax0 = fmaf(x0,  Ax[0], ax0);  gh0 = fmaf(x0,  Wx[0], gh0);               \
        ax0 = fmaf(u1v, Ax[1], ax0);  gh0 = fmaf(u1v, Wx[1], gh0);               \
        ax0 = fmaf(u2v, Ax[2], ax0);  gh0 = fmaf(u2v, Wx[2], gh0);               \
        ax0 = fmaf(u3v, Ax[3], ax0);  gh0 = fmaf(u3v, Wx[3], gh0);               \
        ax1 = fmaf(u4v, Ax[4], ax1);  gh1 = fmaf(u4v, Wx[4], gh1);               \
        ax1 = fmaf(u5v, Ax[5], ax1);  gh1 = fmaf(u5v, Wx[5], gh1);               \
        ax1 = fmaf(u6v, Ax[6], ax1);  gh1 = fmaf(u6v, Wx[6], gh1);               \
        ax1 = fmaf(u7v, Ax[7], ax1);  gh1 = fmaf(u7v, Wx[7], gh1);               \
        XFILL = xbase[((s + 3) & (TT - 1)) * 8 + xoff];  /* prefetch s+3 */      \
        /* GRU1: pair swap gives both z and r pre-activations */                 \
        const float azrC = ax0 + ax1;                                            \
        const float swp = rorkf_<8>(azrC);                                       \
        const float s_own = sgm_(azrC), s_sw = sgm_(swp);                        \
        const float z1 = ishi ? s_sw : s_own;                                    \
        const float r1 = ishi ? s_own : s_sw;                                    \
        const float hh1 = fmaxf(fmaf(r1, ihP, gh0 + gh1), 0.f);                  \
        h1own = fmaf(z1, h1own - hh1, hh1);                                      \
        /* h1 fan-out: W2 taps + next-step GRU1 h-taps */                        \
        const float n0 = h1own;                                                  \
        const float n1 = rorkf_<1>(n0), n2 = rorkf_<2>(n0);                      \
        const float n3 = rorkf_<3>(n0), n4 = rorkf_<4>(n0);                      \
        const float n5 = rorkf_<5>(n0), n6 = rorkf_<6>(n0);                      \
        const float n7 = rorkf_<7>(n0);                                          \
        float hb0 = bD2, hb1 = 0.f;                                              \
        float aN0 = bAzr, aN1 = 0.f, iN0 = bIh, iN1 = 0.f;                       \
        za0 = fmaf(n0, p2z[0], za0);  ra0 = fmaf(n0, p2r[0], ra0);               \
        hb0 = fmaf(n0, p2h[0], hb0);                                             \
        aN0 = fmaf(n0, Ch[0], aN0);   iN0 = fmaf(n0, Qh[0], iN0);                \
        za1 = fmaf(n1, p2z[1], za1);  ra1 = fmaf(n1, p2r[1], ra1);               \
        hb1 = fmaf(n1, p2h[1], hb1);                                             \
        aN1 = fmaf(n1, Ch[1], aN1);   iN1 = fmaf(n1, Qh[1], iN1);                \
        za0 = fmaf(n2, p2z[2], za0);  ra0 = fmaf(n2, p2r[2], ra0);               \
        hb0 = fmaf(n2, p2h[2], hb0);                                             \
        aN0 = fmaf(n2, Ch[2], aN0);   iN0 = fmaf(n2, Qh[2], iN0);                \
        za1 = fmaf(n3, p2z[3], za1);  ra1 = fmaf(n3, p2r[3], ra1);               \
        hb1 = fmaf(n3, p2h[3], hb1);                                             \
        aN1 = fmaf(n3, Ch[3], aN1);   iN1 = fmaf(n3, Qh[3], iN1);                \
        za0 = fmaf(n4, p2z[4], za0);  ra0 = fmaf(n4, p2r[4], ra0);               \
        hb0 = fmaf(n4, p2h[4], hb0);                                             \
        aN0 = fmaf(n4, Ch[4], aN0);   iN0 = fmaf(n4, Qh[4], iN0);                \
        za1 = fmaf(n5, p2z[5], za1);  ra1 = fmaf(n5, p2r[5], ra1);               \
        hb1 = fmaf(n5, p2h[5], hb1);                                             \
        aN1 = fmaf(n5, Ch[5], aN1);   iN1 = fmaf(n5, Qh[5], iN1);                \
        za0 = fmaf(n6, p2z[6], za0);  ra0 = fmaf(n6, p2r[6], ra0);               \
        hb0 = fmaf(n6, p2h[6], hb0);                                             \
        aN0 = fmaf(n6, Ch[6], aN0);   iN0 = fmaf(n6, Qh[6], iN0);                \
        za1 = fmaf(n7, p2z[7], za1);  ra1 = fmaf(n7, p2r[7], ra1);               \
        hb1 = fmaf(n7, p2h[7], hb1);                                             \
        aN1 = fmaf(n7, Ch[7], aN1);   iN1 = fmaf(n7, Qh[7], iN1);                \
        azrP = aN0 + aN1;  ihP = iN0 + iN1;                                      \
        /* GRU2 nonlinearity + state */                                          \
        const float zaC = za0 + za1, raC = ra0 + ra1;                            \
        const float haC = ha0 + ha1, hbC = hb0 + hb1;                            \
        const float z2 = sgm_(zaC), r2 = sgm_(raC);                              \
        const float hh2 = fmaxf(fmaf(r2, haC, hbC), 0.f);                        \
        h2own = fmaf(z2, h2own - hh2, hh2);                                      \
        /* dense for step s-1 (da used h2(s-1)) */                               \
        float e = fmaxf(da0 + da1, 0.f) * woj;                                   \
        e += shrf_<0x118>(e);                                                    \
        e += shrf_<0x114>(e);                                                    \
        e += shrf_<0x112>(e);                                                    \
        e += shrf_<0x111>(e);                                                    \
        if (s > 0) { if (isw) outrow[s - 1] = e + boo; }                         \
    }

    for (int s0 = 0; s0 < TT; s0 += 4) {
        GSTEP(s0 + 0, xA, xA)
        GSTEP(s0 + 1, xB, xB)
        GSTEP(s0 + 2, xC, xC)
        GSTEP(s0 + 3, xA, xA)
        { float t = xB; xB = xC; xC = xA; xA = t; }
    }
#undef GSTEP

    // ---- epilogue: dense for s = 511 from final h2 (fan-out, off-loop) ----
    {
        const float h0 = h2own;
        float da0 = fmaf(h0, wdk[0], bdj), da1 = 0.f;
        const float t1 = rorkf_<1>(h0),  t2  = rorkf_<2>(h0);
        const float t3 = rorkf_<3>(h0),  t4  = rorkf_<4>(h0);
        const float t5 = rorkf_<5>(h0),  t6  = rorkf_<6>(h0);
        const float t7 = rorkf_<7>(h0),  t8  = rorkf_<8>(h0);
        const float t9 = rorkf_<9>(h0),  t10 = rorkf_<10>(h0);
        const float t11 = rorkf_<11>(h0), t12 = rorkf_<12>(h0);
        const float t13 = rorkf_<13>(h0), t14 = rorkf_<14>(h0);
        const float t15 = rorkf_<15>(h0);
        da0 = fmaf(t1, wdk[1], da0);   da1 = fmaf(t2, wdk[2], da1);
        da0 = fmaf(t3, wdk[3], da0);   da1 = fmaf(t4, wdk[4], da1);
        da0 = fmaf(t5, wdk[5], da0);   da1 = fmaf(t6, wdk[6], da1);
        da0 = fmaf(t7, wdk[7], da0);   da1 = fmaf(t8, wdk[8], da1);
        da0 = fmaf(t9, wdk[9], da0);   da1 = fmaf(t10, wdk[10], da1);
        da0 = fmaf(t11, wdk[11], da0); da1 = fmaf(t12, wdk[12], da1);
        da0 = fmaf(t13, wdk[13], da0); da1 = fmaf(t14, wdk[14], da1);
        da0 = fmaf(t15, wdk[15], da0);
        float e = fmaxf(da0 + da1, 0.f) * woj;
        e += shrf_<0x118>(e);
        e += shrf_<0x114>(e);
        e += shrf_<0x112>(e);
        e += shrf_<0x111>(e);
        if (isw) outrow[TT - 1] = e + boo;
    }
}

extern "C" void kernel_launch(void* const* d_in, const int* in_sizes, int n_in,
                              void* d_out, int out_size, void* d_ws, size_t ws_size,
                              hipStream_t stream) {
    const float* x   = (const float*)d_in[0];
    const float* W1  = (const float*)d_in[1];
    const float* Ur1 = (const float*)d_in[2];
    const float* b1  = (const float*)d_in[3];
    const float* W2  = (const float*)d_in[4];
    const float* Ur2 = (const float*)d_in[5];
    const float* b2  = (const float*)d_in[6];
    const float* Wd  = (const float*)d_in[7];
    const float* bd  = (const float*)d_in[8];
    const float* Wo  = (const float*)d_in[9];
    const float* bo  = (const float*)d_in[10];
    float* out = (float*)d_out;

    dim3 grid(4096 / 2);   // 2048 waves: 2 resident waves/SIMD with R8's exact code
    dim3 block(64);        // 2 rows x 16 lanes (groups 1,3 mirror 0,2), zero LDS
    gru_fan2<<<grid, block, 0, stream>>>(x, W1, Ur1, b1, W2, Ur2, b2,
                                         Wd, bd, Wo, bo, out);
}

// Round 14
// 174.616 us; speedup vs baseline: 2.0590x; 2.0590x over previous
//
#include <hip/hip_runtime.h>

#define TT 512
#define LOG2E 1.44269504088896340736f

typedef float f2 __attribute__((ext_vector_type(2)));

// ---- DPP helpers (rows of 16 lanes) ----
template <int N>
__device__ __forceinline__ int rorki_(int v) {           // row_ror:N, depth-1 fan-out
    return __builtin_amdgcn_update_dpp(v, v, 0x120 + N, 0xf, 0xf, true);
}
template <int N>
__device__ __forceinline__ float rorkf_(float v) { return __int_as_float(rorki_<N>(__float_as_int(v))); }
template <int C>
__device__ __forceinline__ float shrf_(float v) {        // row_shr:N, shifted-in -> 0
    return __int_as_float(__builtin_amdgcn_update_dpp(0, __float_as_int(v), C, 0xf, 0xf, true));
}
__device__ __forceinline__ float sgm_(float v) {         // sigmoid, arg pre-scaled by log2e
    return __builtin_amdgcn_rcpf(1.f + __builtin_amdgcn_exp2f(-v));
}
__device__ __forceinline__ f2 pfma_(f2 a, f2 b, f2 c) {  // v_pk_fma_f32: 2 f32 FMAs / instr
    return __builtin_elementwise_fma(a, b, c);
}

__launch_bounds__(64)
__attribute__((amdgpu_waves_per_eu(1, 1)))   // pin full VGPR budget (R8-proven; avoids R10 spill trap)
__global__ void gru_pk4(const float* __restrict__ x,
                        const float* __restrict__ W1, const float* __restrict__ Ur1,
                        const float* __restrict__ b1,
                        const float* __restrict__ W2, const float* __restrict__ Ur2,
                        const float* __restrict__ b2,
                        const float* __restrict__ Wd, const float* __restrict__ bd,
                        const float* __restrict__ Wo, const float* __restrict__ bo,
                        float* __restrict__ out)
{
    const int lane = threadIdx.x & 63;
    const int g    = lane >> 4;         // 4 distinct rows/wave (R8 volume-optimal mapping)
    const int j    = lane & 15;         // GRU2 / dense unit
    const int u1   = j & 7;             // GRU1 unit (pair-duplicated)
    const int hi   = j >> 3;            // 0: z-side, 1: r-side of the GRU1 pair
    const int gcol = u1 + 8 * hi;
    const int row  = blockIdx.x * 4 + g;
    const bool ishi = (hi != 0);
    const bool isw  = (j == 15);        // one store per row

    const float* xbase = x + (size_t)blockIdx.x * 4 * TT * 8;
    const int    xoff  = g * TT * 8 + u1;
    float* outrow = out + (size_t)row * TT;

    // ---- trace the DIRECT ror:k permutation (layout-proof weight order) ----
    int Lk[16];
    Lk[0]  = j;
    Lk[1]  = rorki_<1>(j);   Lk[2]  = rorki_<2>(j);   Lk[3]  = rorki_<3>(j);
    Lk[4]  = rorki_<4>(j);   Lk[5]  = rorki_<5>(j);   Lk[6]  = rorki_<6>(j);
    Lk[7]  = rorki_<7>(j);   Lk[8]  = rorki_<8>(j);   Lk[9]  = rorki_<9>(j);
    Lk[10] = rorki_<10>(j);  Lk[11] = rorki_<11>(j);  Lk[12] = rorki_<12>(j);
    Lk[13] = rorki_<13>(j);  Lk[14] = rorki_<14>(j);  Lk[15] = rorki_<15>(j);

    // ---- packed weights: tap-pair (2k, 2k+1) per f2 ----
    f2 Pz[8], Pr[8], Ph[8], Pd[8];                 // h2 fan (16 taps)
#pragma unroll
    for (int k = 0; k < 8; ++k) {
        const int a = Lk[2 * k], b = Lk[2 * k + 1];
        Pz[k] = f2{LOG2E * Ur2[a * 48 + j],      LOG2E * Ur2[b * 48 + j]};
        Pr[k] = f2{LOG2E * Ur2[a * 48 + 16 + j], LOG2E * Ur2[b * 48 + 16 + j]};
        Ph[k] = f2{Ur2[a * 48 + 32 + j],         Ur2[b * 48 + 32 + j]};
        Pd[k] = f2{Wd[a * 16 + j],               Wd[b * 16 + j]};
    }
    f2 Vz[4], Vr[4], Vh[4], VC[4], VQ[4];          // h1 fan (8 taps)
    f2 Gx[4], Hx[4];                               // x fan (8 taps)
#pragma unroll
    for (int k = 0; k < 4; ++k) {
        const int a = Lk[2 * k] & 7, b = Lk[2 * k + 1] & 7;
        Vz[k] = f2{LOG2E * W2[a * 48 + j],       LOG2E * W2[b * 48 + j]};
        Vr[k] = f2{LOG2E * W2[a * 48 + 16 + j],  LOG2E * W2[b * 48 + 16 + j]};
        Vh[k] = f2{W2[a * 48 + 32 + j],          W2[b * 48 + 32 + j]};
        VC[k] = f2{LOG2E * Ur1[a * 24 + gcol],   LOG2E * Ur1[b * 24 + gcol]};
        VQ[k] = f2{Ur1[a * 24 + 16 + u1],        Ur1[b * 24 + 16 + u1]};
        Gx[k] = f2{LOG2E * W1[a * 24 + gcol],    LOG2E * W1[b * 24 + gcol]};
        Hx[k] = f2{W1[a * 24 + 16 + u1],         W1[b * 24 + 16 + u1]};
    }
    const float bAzr = LOG2E * (b1[gcol] + b1[24 + gcol]);
    const float bGh  = b1[16 + u1];
    const float bIh  = b1[40 + u1];
    const float bA2  = LOG2E * (b2[j] + b2[48 + j]);
    const float bB2  = LOG2E * (b2[16 + j] + b2[64 + j]);
    const float bC2  = b2[80 + j];
    const float bD2  = b2[32 + j];
    const float bdj  = bd[j], woj = Wo[j], boo = bo[0];

    float h1own = 0.f, h2own = 0.f;
    float azrP = bAzr, ihP = bIh;                  // carried GRU1 h-side partials

    float xA = xbase[0 * 8 + xoff];
    float xB = xbase[1 * 8 + xoff];
    float xC = xbase[2 * 8 + xoff];

#define GSTEP(SS, XCUR, XFILL)                                                   \
    {                                                                            \
        const int s = (SS);                                                      \
        /* h2 fan-out: 15 depth-1 DPPs, packed into 8 tap-pairs */               \
        const float h0 = h2own;                                                  \
        f2 tp[8];                                                                \
        tp[0] = f2{h0,             rorkf_<1>(h0)};                               \
        tp[1] = f2{rorkf_<2>(h0),  rorkf_<3>(h0)};                               \
        tp[2] = f2{rorkf_<4>(h0),  rorkf_<5>(h0)};                               \
        tp[3] = f2{rorkf_<6>(h0),  rorkf_<7>(h0)};                               \
        tp[4] = f2{rorkf_<8>(h0),  rorkf_<9>(h0)};                               \
        tp[5] = f2{rorkf_<10>(h0), rorkf_<11>(h0)};                              \
        tp[6] = f2{rorkf_<12>(h0), rorkf_<13>(h0)};                              \
        tp[7] = f2{rorkf_<14>(h0), rorkf_<15>(h0)};                              \
        f2 za = f2{bA2, 0.f}, ra = f2{bB2, 0.f};                                 \
        f2 ha = f2{bC2, 0.f}, da = f2{bdj, 0.f};                                 \
        _Pragma("unroll")                                                        \
        for (int k = 0; k < 8; ++k) {                                            \
            za = pfma_(tp[k], Pz[k], za);  ra = pfma_(tp[k], Pr[k], ra);         \
            ha = pfma_(tp[k], Ph[k], ha);  da = pfma_(tp[k], Pd[k], da);         \
        }                                                                        \
        /* x fan-out: 7 depth-1 DPPs, 4 tap-pairs */                             \
        const float x0 = XCUR;                                                   \
        f2 xp[4];                                                                \
        xp[0] = f2{x0,            rorkf_<1>(x0)};                                \
        xp[1] = f2{rorkf_<2>(x0), rorkf_<3>(x0)};                                \
        xp[2] = f2{rorkf_<4>(x0), rorkf_<5>(x0)};                                \
        xp[3] = f2{rorkf_<6>(x0), rorkf_<7>(x0)};                                \
        f2 axp = f2{azrP, 0.f}, ghp = f2{bGh, 0.f};                              \
        _Pragma("unroll")                                                        \
        for (int k = 0; k < 4; ++k) {                                            \
            axp = pfma_(xp[k], Gx[k], axp);  ghp = pfma_(xp[k], Hx[k], ghp);     \
        }                                                                        \
        XFILL = xbase[((s + 3) & (TT - 1)) * 8 + xoff];  /* prefetch s+3 */      \
        /* GRU1: one sigmoid; partner's sigmoid via ror8 of the result */        \
        const float azrC = axp.x + axp.y;                                        \
        const float s_own = sgm_(azrC);                                          \
        const float s_sw  = rorkf_<8>(s_own);                                    \
        const float z1 = ishi ? s_sw : s_own;                                    \
        const float r1 = ishi ? s_own : s_sw;                                    \
        const float ghxC = ghp.x + ghp.y;                                        \
        const float hh1 = fmaxf(fmaf(r1, ihP, ghxC), 0.f);                       \
        h1own = fmaf(z1, h1own - hh1, hh1);                                      \
        /* h1 fan-out: W2 taps + next-step GRU1 h-taps, 4 tap-pairs */           \
        const float n0 = h1own;                                                  \
        f2 np[4];                                                                \
        np[0] = f2{n0,            rorkf_<1>(n0)};                                \
        np[1] = f2{rorkf_<2>(n0), rorkf_<3>(n0)};                                \
        np[2] = f2{rorkf_<4>(n0), rorkf_<5>(n0)};                                \
        np[3] = f2{rorkf_<6>(n0), rorkf_<7>(n0)};                                \
        f2 hbp = f2{bD2, 0.f}, aNp = f2{bAzr, 0.f}, iNp = f2{bIh, 0.f};          \
        _Pragma("unroll")                                                        \
        for (int k = 0; k < 4; ++k) {                                            \
            za  = pfma_(np[k], Vz[k], za);   ra  = pfma_(np[k], Vr[k], ra);      \
            hbp = pfma_(np[k], Vh[k], hbp);                                      \
            aNp = pfma_(np[k], VC[k], aNp);  iNp = pfma_(np[k], VQ[k], iNp);     \
        }                                                                        \
        azrP = aNp.x + aNp.y;  ihP = iNp.x + iNp.y;                              \
        /* GRU2 nonlinearity + state */                                          \
        const float zaC = za.x + za.y, raC = ra.x + ra.y;                        \
        const float haC = ha.x + ha.y, hbC = hbp.x + hbp.y;                      \
        const float z2 = sgm_(zaC), r2 = sgm_(raC);                              \
        const float hh2 = fmaxf(fmaf(r2, haC, hbC), 0.f);                        \
        h2own = fmaf(z2, h2own - hh2, hh2);                                      \
        /* dense for step s-1 (da used h2(s-1)) */                               \
        float e = fmaxf(da.x + da.y, 0.f) * woj;                                 \
        e += shrf_<0x118>(e);                                                    \
        e += shrf_<0x114>(e);                                                    \
        e += shrf_<0x112>(e);                                                    \
        e += shrf_<0x111>(e);                                                    \
        if (s > 0) { if (isw) outrow[s - 1] = e + boo; }                         \
    }

    for (int s0 = 0; s0 < TT; s0 += 4) {
        GSTEP(s0 + 0, xA, xA)
        GSTEP(s0 + 1, xB, xB)
        GSTEP(s0 + 2, xC, xC)
        GSTEP(s0 + 3, xA, xA)
        { float t = xB; xB = xC; xC = xA; xA = t; }
    }
#undef GSTEP

    // ---- epilogue: dense for s = 511 from final h2 ----
    {
        const float h0 = h2own;
        f2 tp[8];
        tp[0] = f2{h0,             rorkf_<1>(h0)};
        tp[1] = f2{rorkf_<2>(h0),  rorkf_<3>(h0)};
        tp[2] = f2{rorkf_<4>(h0),  rorkf_<5>(h0)};
        tp[3] = f2{rorkf_<6>(h0),  rorkf_<7>(h0)};
        tp[4] = f2{rorkf_<8>(h0),  rorkf_<9>(h0)};
        tp[5] = f2{rorkf_<10>(h0), rorkf_<11>(h0)};
        tp[6] = f2{rorkf_<12>(h0), rorkf_<13>(h0)};
        tp[7] = f2{rorkf_<14>(h0), rorkf_<15>(h0)};
        f2 da = f2{bdj, 0.f};
#pragma unroll
        for (int k = 0; k < 8; ++k) da = pfma_(tp[k], Pd[k], da);
        float e = fmaxf(da.x + da.y, 0.f) * woj;
        e += shrf_<0x118>(e);
        e += shrf_<0x114>(e);
        e += shrf_<0x112>(e);
        e += shrf_<0x111>(e);
        if (isw) outrow[TT - 1] = e + boo;
    }
}

extern "C" void kernel_launch(void* const* d_in, const int* in_sizes, int n_in,
                              void* d_out, int out_size, void* d_ws, size_t ws_size,
                              hipStream_t stream) {
    const float* x   = (const float*)d_in[0];
    const float* W1  = (const float*)d_in[1];
    const float* Ur1 = (const float*)d_in[2];
    const float* b1  = (const float*)d_in[3];
    const float* W2  = (const float*)d_in[4];
    const float* Ur2 = (const float*)d_in[5];
    const float* b2  = (const float*)d_in[6];
    const float* Wd  = (const float*)d_in[7];
    const float* bd  = (const float*)d_in[8];
    const float* Wo  = (const float*)d_in[9];
    const float* bo  = (const float*)d_in[10];
    float* out = (float*)d_out;

    dim3 grid(4096 / 4);   // 1024 waves = 1/SIMD (volume-optimal mapping)
    dim3 block(64);        // 4 rows x 16 lanes, zero LDS
    gru_pk4<<<grid, block, 0, stream>>>(x, W1, Ur1, b1, W2, Ur2, b2,
                                        Wd, bd, Wo, bo, out);
}

// Round 15
// 164.840 us; speedup vs baseline: 2.1811x; 1.0593x over previous
//
#include <hip/hip_runtime.h>

#define TT 512
#define CH 32
#define NCH 16            // 512/32 chunks
#define NPH (NCH + 2)     // phases: A leads, dense trails by 2
#define LOG2E 1.44269504088896340736f

typedef float f2 __attribute__((ext_vector_type(2)));

template <int N>
__device__ __forceinline__ int rorki_(int v) {           // row_ror:N (16-lane rows)
    return __builtin_amdgcn_update_dpp(v, v, 0x120 + N, 0xf, 0xf, true);
}
template <int N>
__device__ __forceinline__ float rorkf_(float v) { return __int_as_float(rorki_<N>(__float_as_int(v))); }
template <int C>
__device__ __forceinline__ float shrf_(float v) {        // row_shr:N, shifted-in -> 0
    return __int_as_float(__builtin_amdgcn_update_dpp(0, __float_as_int(v), C, 0xf, 0xf, true));
}
__device__ __forceinline__ float sgm_(float v) {         // sigmoid, arg pre-scaled by log2e
    return __builtin_amdgcn_rcpf(1.f + __builtin_amdgcn_exp2f(-v));
}
__device__ __forceinline__ f2 pfma_(f2 a, f2 b, f2 c) {  // v_pk_fma_f32
    return __builtin_elementwise_fma(a, b, c);
}

__launch_bounds__(128)
__attribute__((amdgpu_waves_per_eu(2, 2)))   // exactly 2 waves/EU -> 256-VGPR budget
__global__ void gru_ws(const float* __restrict__ x,
                       const float* __restrict__ W1, const float* __restrict__ Ur1,
                       const float* __restrict__ b1,
                       const float* __restrict__ W2, const float* __restrict__ Ur2,
                       const float* __restrict__ b2,
                       const float* __restrict__ Wd, const float* __restrict__ bd,
                       const float* __restrict__ Wo, const float* __restrict__ bo,
                       float* __restrict__ out)
{
    // Feed-forward buffers only; producer/consumer separated by >=1 phase + barrier.
    // h1b layout [buf][step][row][unit]: write banks g*8+u1 -> all 32, conflict-free.
    // h2b: banks (g*16+j)%32 -> 2-way (free, m136).
    __shared__ float h1b[2][CH][4][8];
    __shared__ float h2b[2][CH][4][16];

    const int tid  = threadIdx.x;
    const int wv   = tid >> 6;          // 0: GRU1+dense, 1: GRU2
    const int lane = tid & 63;
    const int g    = lane >> 4;         // row group (4 rows/block)
    const int j    = lane & 15;
    const int u1   = j & 7;
    const int hi   = j >> 3;
    const int gcol = u1 + 8 * hi;
    const bool ishi = (hi != 0);
    const bool isw  = (j == 15);

    // ---- trace the ror:k permutation (layout-proof rotation weight order) ----
    int Lk[16];
    Lk[0]  = j;
    Lk[1]  = rorki_<1>(j);   Lk[2]  = rorki_<2>(j);   Lk[3]  = rorki_<3>(j);
    Lk[4]  = rorki_<4>(j);   Lk[5]  = rorki_<5>(j);   Lk[6]  = rorki_<6>(j);
    Lk[7]  = rorki_<7>(j);   Lk[8]  = rorki_<8>(j);   Lk[9]  = rorki_<9>(j);
    Lk[10] = rorki_<10>(j);  Lk[11] = rorki_<11>(j);  Lk[12] = rorki_<12>(j);
    Lk[13] = rorki_<13>(j);  Lk[14] = rorki_<14>(j);  Lk[15] = rorki_<15>(j);

    if (wv == 0) {
        // ================= wave A: GRU1 (in-register) + dense (h2 from LDS) =====
        f2 Gx[4], Hx[4], VC[4], VQ[4];          // rotation-ordered GRU1 taps
#pragma unroll
        for (int k = 0; k < 4; ++k) {
            const int a = Lk[2 * k] & 7, b = Lk[2 * k + 1] & 7;
            Gx[k] = f2{LOG2E * W1[a * 24 + gcol],  LOG2E * W1[b * 24 + gcol]};
            Hx[k] = f2{W1[a * 24 + 16 + u1],       W1[b * 24 + 16 + u1]};
            VC[k] = f2{LOG2E * Ur1[a * 24 + gcol], LOG2E * Ur1[b * 24 + gcol]};
            VQ[k] = f2{Ur1[a * 24 + 16 + u1],      Ur1[b * 24 + 16 + u1]};
        }
        f2 Pd[8];                               // dense taps, NATURAL order (h2 from LDS)
#pragma unroll
        for (int k = 0; k < 8; ++k)
            Pd[k] = f2{Wd[(2 * k) * 16 + j], Wd[(2 * k + 1) * 16 + j]};
        const float bAzr = LOG2E * (b1[gcol] + b1[24 + gcol]);
        const float bGh  = b1[16 + u1];
        const float bIh  = b1[40 + u1];
        const float bdj  = bd[j], woj = Wo[j], boo = bo[0];

        const float* xbase = x + (size_t)blockIdx.x * 4 * TT * 8;
        const int    xoff  = g * TT * 8 + u1;
        float* outrow = out + (size_t)(blockIdx.x * 4 + g) * TT;

        float h1own = 0.f, azrP = bAzr, ihP = bIh;
        float xA = xbase[0 * 8 + xoff];
        float xB = xbase[1 * 8 + xoff];
        float xC = xbase[2 * 8 + xoff];
        float4 hA0, hA1, hA2, hA3, hB0, hB1, hB2, hB3;   // dense ping-pong

#define G1STEP(TG, SL, XCUR, XFILL)                                          \
    {                                                                        \
        const float x0 = XCUR;                                               \
        const f2 xp0 = f2{x0,            rorkf_<1>(x0)};                     \
        const f2 xp1 = f2{rorkf_<2>(x0), rorkf_<3>(x0)};                     \
        const f2 xp2 = f2{rorkf_<4>(x0), rorkf_<5>(x0)};                     \
        const f2 xp3 = f2{rorkf_<6>(x0), rorkf_<7>(x0)};                     \
        f2 axp = f2{azrP, 0.f}, ghp = f2{bGh, 0.f};                          \
        axp = pfma_(xp0, Gx[0], axp);  ghp = pfma_(xp0, Hx[0], ghp);         \
        axp = pfma_(xp1, Gx[1], axp);  ghp = pfma_(xp1, Hx[1], ghp);         \
        axp = pfma_(xp2, Gx[2], axp);  ghp = pfma_(xp2, Hx[2], ghp);         \
        axp = pfma_(xp3, Gx[3], axp);  ghp = pfma_(xp3, Hx[3], ghp);         \
        XFILL = xbase[(((TG) + 3) & (TT - 1)) * 8 + xoff];                   \
        const float azrC = axp.x + axp.y;                                    \
        const float s_own = sgm_(azrC);                                      \
        const float s_sw  = rorkf_<8>(s_own);                                \
        const float z1 = ishi ? s_sw : s_own;                                \
        const float r1 = ishi ? s_own : s_sw;                                \
        const float hh1 = fmaxf(fmaf(r1, ihP, ghp.x + ghp.y), 0.f);          \
        h1own = fmaf(z1, h1own - hh1, hh1);                                  \
        const float n0 = h1own;                                              \
        const f2 np0 = f2{n0,            rorkf_<1>(n0)};                     \
        const f2 np1 = f2{rorkf_<2>(n0), rorkf_<3>(n0)};                     \
        const f2 np2 = f2{rorkf_<4>(n0), rorkf_<5>(n0)};                     \
        const f2 np3 = f2{rorkf_<6>(n0), rorkf_<7>(n0)};                     \
        f2 aNp = f2{bAzr, 0.f}, iNp = f2{bIh, 0.f};                          \
        aNp = pfma_(np0, VC[0], aNp);  iNp = pfma_(np0, VQ[0], iNp);         \
        aNp = pfma_(np1, VC[1], aNp);  iNp = pfma_(np1, VQ[1], iNp);         \
        aNp = pfma_(np2, VC[2], aNp);  iNp = pfma_(np2, VQ[2], iNp);         \
        aNp = pfma_(np3, VC[3], aNp);  iNp = pfma_(np3, VQ[3], iNp);         \
        azrP = aNp.x + aNp.y;  ihP = iNp.x + iNp.y;                          \
        h1b[p & 1][SL][g][u1] = h1own;                                       \
    }

#define DSTEP(DL, C0, C1, C2, C3, N0, N1, N2, N3, DN)                        \
    {                                                                        \
        f2 da = f2{bdj, 0.f};                                                \
        da = pfma_(f2{C0.x, C0.y}, Pd[0], da);                               \
        da = pfma_(f2{C0.z, C0.w}, Pd[1], da);                               \
        da = pfma_(f2{C1.x, C1.y}, Pd[2], da);                               \
        da = pfma_(f2{C1.z, C1.w}, Pd[3], da);                               \
        da = pfma_(f2{C2.x, C2.y}, Pd[4], da);                               \
        da = pfma_(f2{C2.z, C2.w}, Pd[5], da);                               \
        da = pfma_(f2{C3.x, C3.y}, Pd[6], da);                               \
        da = pfma_(f2{C3.z, C3.w}, Pd[7], da);                               \
        N0 = *(const float4*)&h2b[p & 1][DN][g][0];                          \
        N1 = *(const float4*)&h2b[p & 1][DN][g][4];                          \
        N2 = *(const float4*)&h2b[p & 1][DN][g][8];                          \
        N3 = *(const float4*)&h2b[p & 1][DN][g][12];                         \
        float e = fmaxf(da.x + da.y, 0.f) * woj;                             \
        e += shrf_<0x118>(e);                                                \
        e += shrf_<0x114>(e);                                                \
        e += shrf_<0x112>(e);                                                \
        e += shrf_<0x111>(e);                                                \
        if (isw) outd[DL] = e + boo;                                         \
    }

        for (int p = 0; p < NPH; ++p) {
            if (p < 2) {
                // GRU1 only
                const int t0 = p * CH;
                for (int s = 0; s < CH; s += 4) {
                    G1STEP(t0 + s + 0, s + 0, xA, xA)
                    G1STEP(t0 + s + 1, s + 1, xB, xB)
                    G1STEP(t0 + s + 2, s + 2, xC, xC)
                    G1STEP(t0 + s + 3, s + 3, xA, xA)
                    { float t = xB; xB = xC; xC = xA; xA = t; }
                }
            } else if (p < NCH) {
                // GRU1 + dense (chunk p-2) interleaved
                const int t0 = p * CH;
                float* outd = outrow + (p - 2) * CH;
                hA0 = *(const float4*)&h2b[p & 1][0][g][0];
                hA1 = *(const float4*)&h2b[p & 1][0][g][4];
                hA2 = *(const float4*)&h2b[p & 1][0][g][8];
                hA3 = *(const float4*)&h2b[p & 1][0][g][12];
                for (int s = 0; s < CH; s += 4) {
                    G1STEP(t0 + s + 0, s + 0, xA, xA)
                    DSTEP(s + 0, hA0, hA1, hA2, hA3, hB0, hB1, hB2, hB3, s + 1)
                    G1STEP(t0 + s + 1, s + 1, xB, xB)
                    DSTEP(s + 1, hB0, hB1, hB2, hB3, hA0, hA1, hA2, hA3, s + 2)
                    G1STEP(t0 + s + 2, s + 2, xC, xC)
                    DSTEP(s + 2, hA0, hA1, hA2, hA3, hB0, hB1, hB2, hB3, s + 3)
                    G1STEP(t0 + s + 3, s + 3, xA, xA)
                    DSTEP(s + 3, hB0, hB1, hB2, hB3, hA0, hA1, hA2, hA3, (s + 4) & (CH - 1))
                    { float t = xB; xB = xC; xC = xA; xA = t; }
                }
            } else {
                // dense only (chunks 14, 15)
                float* outd = outrow + (p - 2) * CH;
                hA0 = *(const float4*)&h2b[p & 1][0][g][0];
                hA1 = *(const float4*)&h2b[p & 1][0][g][4];
                hA2 = *(const float4*)&h2b[p & 1][0][g][8];
                hA3 = *(const float4*)&h2b[p & 1][0][g][12];
                for (int s = 0; s < CH; s += 4) {
                    DSTEP(s + 0, hA0, hA1, hA2, hA3, hB0, hB1, hB2, hB3, s + 1)
                    DSTEP(s + 1, hB0, hB1, hB2, hB3, hA0, hA1, hA2, hA3, s + 2)
                    DSTEP(s + 2, hA0, hA1, hA2, hA3, hB0, hB1, hB2, hB3, s + 3)
                    DSTEP(s + 3, hB0, hB1, hB2, hB3, hA0, hA1, hA2, hA3, (s + 4) & (CH - 1))
                }
            }
            __syncthreads();
        }
#undef G1STEP
#undef DSTEP
    } else {
        // ================= wave B: GRU2 (in-register; h1 from LDS, natural order) =====
        f2 Pz[8], Pr[8], Ph[8];                 // h2 fan, rotation-ordered
#pragma unroll
        for (int k = 0; k < 8; ++k) {
            const int a = Lk[2 * k], b = Lk[2 * k + 1];
            Pz[k] = f2{LOG2E * Ur2[a * 48 + j],      LOG2E * Ur2[b * 48 + j]};
            Pr[k] = f2{LOG2E * Ur2[a * 48 + 16 + j], LOG2E * Ur2[b * 48 + 16 + j]};
            Ph[k] = f2{Ur2[a * 48 + 32 + j],         Ur2[b * 48 + 32 + j]};
        }
        f2 Vz[4], Vr[4], Vh[4];                 // W2 taps, NATURAL order
#pragma unroll
        for (int k = 0; k < 4; ++k) {
            Vz[k] = f2{LOG2E * W2[(2 * k) * 48 + j],      LOG2E * W2[(2 * k + 1) * 48 + j]};
            Vr[k] = f2{LOG2E * W2[(2 * k) * 48 + 16 + j], LOG2E * W2[(2 * k + 1) * 48 + 16 + j]};
            Vh[k] = f2{W2[(2 * k) * 48 + 32 + j],         W2[(2 * k + 1) * 48 + 32 + j]};
        }
        const float bA2 = LOG2E * (b2[j] + b2[48 + j]);
        const float bB2 = LOG2E * (b2[16 + j] + b2[64 + j]);
        const float bC2 = b2[80 + j];
        const float bD2 = b2[32 + j];

        float h2own = 0.f;
        float4 kA0, kA1, kB0, kB1;              // h1 ping-pong

#define G2STEP(SL, K0, K1, M0, M1, SN)                                       \
    {                                                                        \
        const float h0 = h2own;                                              \
        const f2 tp0 = f2{h0,             rorkf_<1>(h0)};                    \
        const f2 tp1 = f2{rorkf_<2>(h0),  rorkf_<3>(h0)};                    \
        const f2 tp2 = f2{rorkf_<4>(h0),  rorkf_<5>(h0)};                    \
        const f2 tp3 = f2{rorkf_<6>(h0),  rorkf_<7>(h0)};                    \
        const f2 tp4 = f2{rorkf_<8>(h0),  rorkf_<9>(h0)};                    \
        const f2 tp5 = f2{rorkf_<10>(h0), rorkf_<11>(h0)};                   \
        const f2 tp6 = f2{rorkf_<12>(h0), rorkf_<13>(h0)};                   \
        const f2 tp7 = f2{rorkf_<14>(h0), rorkf_<15>(h0)};                   \
        f2 za = f2{bA2, 0.f}, ra = f2{bB2, 0.f}, ha = f2{bC2, 0.f};          \
        za = pfma_(tp0, Pz[0], za); ra = pfma_(tp0, Pr[0], ra); ha = pfma_(tp0, Ph[0], ha); \
        za = pfma_(tp1, Pz[1], za); ra = pfma_(tp1, Pr[1], ra); ha = pfma_(tp1, Ph[1], ha); \
        za = pfma_(tp2, Pz[2], za); ra = pfma_(tp2, Pr[2], ra); ha = pfma_(tp2, Ph[2], ha); \
        za = pfma_(tp3, Pz[3], za); ra = pfma_(tp3, Pr[3], ra); ha = pfma_(tp3, Ph[3], ha); \
        za = pfma_(tp4, Pz[4], za); ra = pfma_(tp4, Pr[4], ra); ha = pfma_(tp4, Ph[4], ha); \
        za = pfma_(tp5, Pz[5], za); ra = pfma_(tp5, Pr[5], ra); ha = pfma_(tp5, Ph[5], ha); \
        za = pfma_(tp6, Pz[6], za); ra = pfma_(tp6, Pr[6], ra); ha = pfma_(tp6, Ph[6], ha); \
        za = pfma_(tp7, Pz[7], za); ra = pfma_(tp7, Pr[7], ra); ha = pfma_(tp7, Ph[7], ha); \
        const f2 q0 = f2{K0.x, K0.y}, q1 = f2{K0.z, K0.w};                   \
        const f2 q2 = f2{K1.x, K1.y}, q3 = f2{K1.z, K1.w};                   \
        f2 hbp = f2{bD2, 0.f};                                               \
        za = pfma_(q0, Vz[0], za); ra = pfma_(q0, Vr[0], ra); hbp = pfma_(q0, Vh[0], hbp); \
        za = pfma_(q1, Vz[1], za); ra = pfma_(q1, Vr[1], ra); hbp = pfma_(q1, Vh[1], hbp); \
        za = pfma_(q2, Vz[2], za); ra = pfma_(q2, Vr[2], ra); hbp = pfma_(q2, Vh[2], hbp); \
        za = pfma_(q3, Vz[3], za); ra = pfma_(q3, Vr[3], ra); hbp = pfma_(q3, Vh[3], hbp); \
        M0 = *(const float4*)&h1b[(p - 1) & 1][SN][g][0];                    \
        M1 = *(const float4*)&h1b[(p - 1) & 1][SN][g][4];                    \
        const float z2 = sgm_(za.x + za.y), r2 = sgm_(ra.x + ra.y);          \
        const float hh2 = fmaxf(fmaf(r2, ha.x + ha.y, hbp.x + hbp.y), 0.f);  \
        h2own = fmaf(z2, h2own - hh2, hh2);                                  \
        h2b[(p - 1) & 1][SL][g][j] = h2own;                                  \
    }

        for (int p = 0; p < NPH; ++p) {
            if (p >= 1 && p <= NCH) {
                kA0 = *(const float4*)&h1b[(p - 1) & 1][0][g][0];
                kA1 = *(const float4*)&h1b[(p - 1) & 1][0][g][4];
                for (int s = 0; s < CH; s += 2) {
                    G2STEP(s + 0, kA0, kA1, kB0, kB1, s + 1)
                    G2STEP(s + 1, kB0, kB1, kA0, kA1, (s + 2) & (CH - 1))
                }
            }
            __syncthreads();
        }
#undef G2STEP
    }
}

extern "C" void kernel_launch(void* const* d_in, const int* in_sizes, int n_in,
                              void* d_out, int out_size, void* d_ws, size_t ws_size,
                              hipStream_t stream) {
    const float* x   = (const float*)d_in[0];
    const float* W1  = (const float*)d_in[1];
    const float* Ur1 = (const float*)d_in[2];
    const float* b1  = (const float*)d_in[3];
    const float* W2  = (const float*)d_in[4];
    const float* Ur2 = (const float*)d_in[5];
    const float* b2  = (const float*)d_in[6];
    const float* Wd  = (const float*)d_in[7];
    const float* bd  = (const float*)d_in[8];
    const float* Wo  = (const float*)d_in[9];
    const float* bo  = (const float*)d_in[10];
    float* out = (float*)d_out;

    dim3 grid(4096 / 4);   // 1024 blocks x 2 waves = 2048 waves = 2/SIMD, true split
    dim3 block(128);       // wave 0: GRU1+dense, wave 1: GRU2; 4 rows/block
    gru_ws<<<grid, block, 0, stream>>>(x, W1, Ur1, b1, W2, Ur2, b2,
                                       Wd, bd, Wo, bo, out);
}